// Round 3
// baseline (162.590 us; speedup 1.0000x reference)
//
#include <hip/hip_runtime.h>
#include <cstdint>

#define NRAD 4096
#define NLID 16384
#define KMIX 8
#define TOPK 10
#define CF   16
#define LOG2PI 1.8378770664093453f

static constexpr unsigned INF_D2 = 62851u;   // > max real d2 (40^2 + 2*175^2 = 62850)

// ---------------------------------------------------------------- helpers
__device__ __forceinline__ void insert_key(unsigned (&t)[TOPK], unsigned key) {
    // t ascending; branch-free exact insert of key into 10 smallest.
#pragma unroll
    for (int i = TOPK - 1; i >= 1; --i) {
        unsigned hi = key > t[i - 1] ? key : t[i - 1];
        t[i] = hi < t[i] ? hi : t[i];
    }
    t[0] = key < t[0] ? key : t[0];
}

__device__ __forceinline__ void merge10(unsigned (&t)[TOPK], int lane,
                                        unsigned& mine, unsigned& first, unsigned& tenth) {
#pragma unroll
    for (int r = 0; r < TOPK; ++r) {
        unsigned v = t[0];
#pragma unroll
        for (int off = 32; off >= 1; off >>= 1) {
            unsigned o = __shfl_xor(v, off, 64);
            v = o < v ? o : v;
        }
        if (t[0] == v) {                       // unique keys -> exactly one popper
#pragma unroll
            for (int i = 0; i < TOPK - 1; ++i) t[i] = t[i + 1];
            t[TOPK - 1] = 0xFFFFFFFFu;
        }
        if (lane == r) mine = v;
        if (r == 0) first = v;
        if (r == TOPK - 1) tenth = v;
    }
}

__device__ __forceinline__ float waveReduceSum(float v) {
#pragma unroll
    for (int off = 32; off >= 1; off >>= 1) v += __shfl_down(v, off, 64);
    return v;
}

// ---------------------------------------------------------------- prep
// 4 blocks x 1024 threads; block b owns batch b. LDS cursors -> no pre-zeroed
// global state. ALL global loads are register-staged up-front (16 int4 + 4 int)
// so their latencies overlap, instead of one load per serial ballot-chain iter.
// Also bins radar rows by batch into rbin (topk locality). Block 0 zeroes
// accum/dctr (visible to next dispatch via stream ordering).
__global__ __launch_bounds__(1024) void prep_kernel(
        const int* __restrict__ lidar_indices,
        const int* __restrict__ radar_indices,
        unsigned* __restrict__ packed_full,
        uint2* __restrict__ compacted,
        int* __restrict__ rbin,
        int* __restrict__ ctrl) {   // [0..3]=lidar cnt [4..7]=accum [8]=dctr [12..15]=radar cnt
    __shared__ int lcur, rcur;
    int tid = threadIdx.x, lane = tid & 63, myb = blockIdx.x;
    if (tid == 0) { lcur = 0; rcur = 0; }

    // stage ALL loads up-front (static indices -> registers, not scratch)
    int4 li[NLID / 1024];
#pragma unroll
    for (int it = 0; it < NLID / 1024; ++it)
        li[it] = ((const int4*)lidar_indices)[it * 1024 + tid];
    int rb4[NRAD / 1024];
#pragma unroll
    for (int it = 0; it < NRAD / 1024; ++it)
        rb4[it] = ((const int4*)radar_indices)[it * 1024 + tid].x;

    __syncthreads();

    // lidar: pack + batch-compact (scatter order nondeterministic == fine,
    // top-k over keys is order-independent)
#pragma unroll
    for (int it = 0; it < NLID / 1024; ++it) {
        int i = it * 1024 + tid;
        unsigned pos = ((unsigned)li[it].y << 16) | ((unsigned)li[it].z << 8) | (unsigned)li[it].w;
        bool mine = (li[it].x == myb);
        if (mine) packed_full[i] = ((unsigned)li[it].x << 22) | pos;
        unsigned long long mask = __ballot(mine);
        if (mine) {
            int leader = __ffsll(mask) - 1;
            int off = (int)__popcll(mask & ((1ull << lane) - 1ull));
            int s = 0;
            if (lane == leader) s = atomicAdd(&lcur, (int)__popcll(mask));
            s = __shfl(s, leader, 64);
            compacted[myb * NLID + s + off] = make_uint2(pos, (unsigned)i);
        }
    }

    // radar: bin row ids by batch (row->result is order-independent)
#pragma unroll
    for (int it = 0; it < NRAD / 1024; ++it) {
        int r = it * 1024 + tid;
        bool mine = (rb4[it] == myb);
        unsigned long long mask = __ballot(mine);
        if (mine) {
            int leader = __ffsll(mask) - 1;
            int off = (int)__popcll(mask & ((1ull << lane) - 1ull));
            int s = 0;
            if (lane == leader) s = atomicAdd(&rcur, (int)__popcll(mask));
            s = __shfl(s, leader, 64);
            rbin[myb * NRAD + s + off] = r;
        }
    }

    __syncthreads();
    if (tid == 0) { ctrl[myb] = lcur; ctrl[12 + myb] = rcur; }
    if (myb == 0 && tid >= 64 && tid < 69) ctrl[4 + (tid - 64)] = 0;  // accum[4] + dctr
}

// ---------------------------------------------------------------- fused top-10 NN + MDN/occ/int
// One wave per radar row (batch-grouped via rbin). After the wave finds its
// row's top-10 (indices live in registers: lane t holds 'mine'), the SAME
// wave computes the MDN/occ/int terms for its 10 pairs (lanes 0-9), reduces
// across the block, and atomically accumulates. Last block finalizes out[0].
// No nn/matched round-trip through memory; one dispatch fewer.
__global__ __launch_bounds__(256) void topk_mdn_kernel(
        const uint2* __restrict__ compacted,
        const unsigned* __restrict__ packed_full,
        int* __restrict__ ctrl,               // counts (ro) + accum/dctr (rw)
        const int* __restrict__ rbin,
        const int* __restrict__ radar_indices,
        const int* __restrict__ lidar_indices,
        const float* __restrict__ mu_off, const float* __restrict__ log_sig_off,
        const float* __restrict__ mu_int, const float* __restrict__ occ_logit,
        const float* __restrict__ mix_logit, const float* __restrict__ lidar_features,
        float* __restrict__ out) {
    float* accum = (float*)(ctrl + 4);
    unsigned* dctr = (unsigned*)(ctrl + 8);
    int lane = threadIdx.x & 63;
    int g = blockIdx.x * 4 + (threadIdx.x >> 6);          // position in batch-grouped order
    int r0 = ctrl[12], r1 = ctrl[13], r2 = ctrl[14];
    int cum1 = r0, cum2 = r0 + r1, cum3 = cum2 + r2;
    int gb = (g >= cum1) + (g >= cum2) + (g >= cum3);
    int gbase = gb == 0 ? 0 : (gb == 1 ? cum1 : (gb == 2 ? cum2 : cum3));
    int row = rbin[gb * NRAD + (g - gbase)];

    int4 ri = ((const int4*)radar_indices)[row];
    int rb = ri.x, rz = ri.y, ry = ri.z, rx = ri.w;
    int c_cnt = ctrl[rb];

    unsigned t[TOPK];
#pragma unroll
    for (int i = 0; i < TOPK; ++i) t[i] = 0xFFFFFFFFu;

    const uint4* src = (const uint4*)(compacted + rb * NLID);  // 16B aligned
    int iters = (c_cnt + 127) >> 7;
    uint4 q = src[lane];
    for (int it = 0; it < iters; ++it) {
        uint4 qn = q;
        if (it + 1 < iters) qn = src[(it + 1) * 64 + lane];    // prefetch next
        int c0 = (it * 64 + lane) * 2;
        {
            int dz = (int)((q.x >> 16) & 63u)  - rz;
            int dy = (int)((q.x >> 8)  & 255u) - ry;
            int dx = (int)(q.x & 255u)         - rx;
            unsigned d2 = (unsigned)(__mul24(dz, dz) + __mul24(dy, dy) + __mul24(dx, dx));
            unsigned key = (c0 < c_cnt) ? ((d2 << 14) | q.y) : 0xFFFFFFFFu;
            if (key < t[TOPK - 1]) insert_key(t, key);
        }
        {
            int dz = (int)((q.z >> 16) & 63u)  - rz;
            int dy = (int)((q.z >> 8)  & 255u) - ry;
            int dx = (int)(q.z & 255u)         - rx;
            unsigned d2 = (unsigned)(__mul24(dz, dz) + __mul24(dy, dy) + __mul24(dx, dx));
            unsigned key = (c0 + 1 < c_cnt) ? ((d2 << 14) | q.w) : 0xFFFFFFFFu;
            if (key < t[TOPK - 1]) insert_key(t, key);
        }
        q = qn;
    }

    unsigned mine = 0, first = 0, tenth = 0;
    merge10(t, lane, mine, first, tenth);
    bool matched = true;   // normal path: >=10 same-batch candidates exist

    if (tenth == 0xFFFFFFFFu) {
        // Degenerate row (<10 same-batch lidar): exact full scan w/ INF keys.
#pragma unroll
        for (int i = 0; i < TOPK; ++i) t[i] = 0xFFFFFFFFu;
        for (int it = 0; it < NLID / 256; ++it) {
            uint4 p4 = ((const uint4*)packed_full)[it * 64 + lane];
            unsigned base = it * 256 + lane * 4;
            unsigned ps[4] = {p4.x, p4.y, p4.z, p4.w};
#pragma unroll
            for (int j = 0; j < 4; ++j) {
                unsigned p = ps[j];
                int b  = (int)(p >> 22);
                int dz = (int)((p >> 16) & 63u)  - rz;
                int dy = (int)((p >> 8)  & 255u) - ry;
                int dx = (int)(p & 255u)         - rx;
                unsigned d2 = (unsigned)(__mul24(dz, dz) + __mul24(dy, dy) + __mul24(dx, dx));
                unsigned hi = (b == rb) ? d2 : INF_D2;
                insert_key(t, (hi << 14) | (base + j));
            }
        }
        merge10(t, lane, mine, first, tenth);
        matched = first < (INF_D2 << 14);
    }

    // ---------------- fused MDN phase (lane t < 10 owns pair (row, t)) ----
    int n = row;
    float mf = matched ? 1.f : 0.f;                 // wave-uniform
    int nni = (int)(mine & 0x3FFFu);                // lanes >=10: mine==0 -> safe idx 0
    int4 li = ((const int4*)lidar_indices)[nni];
    float y0 = mf * (float)(li.w - rx);
    float y1 = mf * (float)(li.z - ry);
    float y2 = mf * (float)(li.y - rz);

    float mix[KMIX];
    float mmax = -1e30f;
#pragma unroll
    for (int k = 0; k < KMIX; ++k) {
        mix[k] = mix_logit[n * KMIX + k];
        mmax = fmaxf(mmax, mix[k]);
    }
    float msum = 0.f;
#pragma unroll
    for (int k = 0; k < KMIX; ++k) msum += expf(mix[k] - mmax);
    float logZ = mmax + logf(msum);

    float lpost[KMIX];
    float pmax = -1e30f;
#pragma unroll
    for (int k = 0; k < KMIX; ++k) {
        int bidx = (n * KMIX + k) * 3;
        float mu0 = mu_off[bidx + 0], mu1 = mu_off[bidx + 1], mu2 = mu_off[bidx + 2];
        float l0 = log_sig_off[bidx + 0], l1 = log_sig_off[bidx + 1], l2 = log_sig_off[bidx + 2];
        float s0 = expf(2.f * l0) + 1e-12f;
        float s1 = expf(2.f * l1) + 1e-12f;
        float s2 = expf(2.f * l2) + 1e-12f;
        float d0 = y0 - mu0, d1 = y1 - mu1, d2v = y2 - mu2;
        float qv = d0 * d0 / s0 + d1 * d1 / s1 + d2v * d2v / s2
                 + 2.f * (l0 + l1 + l2) + 3.f * LOG2PI;
        lpost[k] = -0.5f * qv + (mix[k] - logZ);
        pmax = fmaxf(pmax, lpost[k]);
    }
    float ex[KMIX];
    float se = 0.f;
#pragma unroll
    for (int k = 0; k < KMIX; ++k) { ex[k] = expf(lpost[k] - pmax); se += ex[k]; }
    float logp = pmax + logf(se);

    float gt = 0.f;
    if (matched) {
        const float* lf = lidar_features + nni * CF;
        gt = 0.25f * (lf[3] + lf[7] + lf[11] + lf[15]);
    }
    float inv_se = 1.f / se;
    float isum = 0.f;
#pragma unroll
    for (int k = 0; k < KMIX; ++k)
        isum += ex[k] * inv_se * fabsf(mu_int[n * KMIX + k] - gt);

    float lp = (lane < TOPK) ? mf * logp : 0.f;
    float ip = (lane < TOPK) ? mf * isum : 0.f;
    float oc = 0.f, mc = 0.f;
    if (lane == 0) {
        float oa = -1e30f;
#pragma unroll
        for (int k = 0; k < KMIX; ++k) oa = fmaxf(oa, occ_logit[n * KMIX + k]);
        float soft_abs = log1pf(expf(-fabsf(oa)));
        oc = mf * (soft_abs + fmaxf(-oa, 0.f)) + (1.f - mf) * (soft_abs + fmaxf(oa, 0.f));
        mc = mf;
    }

    lp = waveReduceSum(lp); ip = waveReduceSum(ip);
    oc = waveReduceSum(oc); mc = waveReduceSum(mc);
    __shared__ float sA[4], sB[4], sC[4], sD[4];
    int wid = threadIdx.x >> 6;
    if (lane == 0) { sA[wid] = lp; sB[wid] = ip; sC[wid] = oc; sD[wid] = mc; }
    __syncthreads();
    if (threadIdx.x == 0) {
        atomicAdd(&accum[0], sA[0] + sA[1] + sA[2] + sA[3]);
        atomicAdd(&accum[1], sB[0] + sB[1] + sB[2] + sB[3]);
        atomicAdd(&accum[2], sC[0] + sC[1] + sC[2] + sC[3]);
        atomicAdd(&accum[3], sD[0] + sD[1] + sD[2] + sD[3]);
        __threadfence();
        unsigned done = atomicAdd(dctr, 1u);
        if (done == gridDim.x - 1) {          // last block finalizes
            __threadfence();
            float a = __hip_atomic_load(&accum[0], __ATOMIC_RELAXED, __HIP_MEMORY_SCOPE_AGENT);
            float b = __hip_atomic_load(&accum[1], __ATOMIC_RELAXED, __HIP_MEMORY_SCOPE_AGENT);
            float c = __hip_atomic_load(&accum[2], __ATOMIC_RELAXED, __HIP_MEMORY_SCOPE_AGENT);
            float d = __hip_atomic_load(&accum[3], __ATOMIC_RELAXED, __HIP_MEMORY_SCOPE_AGENT);
            float occ_loss = c / (float)NRAD;
            float mdn_nll  = -a / (d * (float)TOPK);
            float int_loss = b / (d * (float)TOPK * (float)KMIX);
            out[0] = 0.2f * occ_loss + mdn_nll + 0.1f * int_loss;
        }
    }
}

// ---------------------------------------------------------------- launch
extern "C" void kernel_launch(void* const* d_in, const int* in_sizes, int n_in,
                              void* d_out, int out_size, void* d_ws, size_t ws_size,
                              hipStream_t stream) {
    const float* mu_off         = (const float*)d_in[0];
    const float* log_sig_off    = (const float*)d_in[1];
    const float* mu_int         = (const float*)d_in[2];
    const float* occ_logit      = (const float*)d_in[3];
    const float* mix_logit      = (const float*)d_in[4];
    const float* lidar_features = (const float*)d_in[5];
    const int*   radar_indices  = (const int*)d_in[6];
    const int*   lidar_indices  = (const int*)d_in[7];
    float* out = (float*)d_out;

    char* ws = (char*)d_ws;
    unsigned* packed_full = (unsigned*)(ws + 0);         //  64 KB
    uint2*    compacted   = (uint2*)(ws + 65536);        //  4*16384*8 = 512 KB
    int*      ctrl        = (int*)(ws + 589824);         //  64 B (cnt/accum/dctr/rcnt)
    int*      rbin        = (int*)(ws + 589888);         //  64 KB

    hipLaunchKernelGGL(prep_kernel, dim3(4), dim3(1024), 0, stream,
                       lidar_indices, radar_indices, packed_full, compacted, rbin, ctrl);
    hipLaunchKernelGGL(topk_mdn_kernel, dim3(NRAD / 4), dim3(256), 0, stream,
                       compacted, packed_full, ctrl, rbin, radar_indices, lidar_indices,
                       mu_off, log_sig_off, mu_int, occ_logit, mix_logit,
                       lidar_features, out);
}

// Round 4
// 112.534 us; speedup vs baseline: 1.4448x; 1.4448x over previous
//
#include <hip/hip_runtime.h>
#include <cstdint>

#define NRAD 4096
#define NLID 16384
#define KMIX 8
#define TOPK 10
#define CF   16
#define NBIN 176
#define LOG2PI 1.8378770664093453f

static constexpr unsigned INF_D2 = 62851u;   // > max real d2 (40^2 + 2*175^2 = 62850)

// ---------------------------------------------------------------- helpers
__device__ __forceinline__ void insert_key(unsigned (&t)[TOPK], unsigned key) {
    // t ascending; branch-free exact insert of key into 10 smallest.
#pragma unroll
    for (int i = TOPK - 1; i >= 1; --i) {
        unsigned hi = key > t[i - 1] ? key : t[i - 1];
        t[i] = hi < t[i] ? hi : t[i];
    }
    t[0] = key < t[0] ? key : t[0];
}

__device__ __forceinline__ void merge10(unsigned (&t)[TOPK], int lane,
                                        unsigned& mine, unsigned& first, unsigned& tenth) {
#pragma unroll
    for (int r = 0; r < TOPK; ++r) {
        unsigned v = t[0];
#pragma unroll
        for (int off = 32; off >= 1; off >>= 1) {
            unsigned o = __shfl_xor(v, off, 64);
            v = o < v ? o : v;
        }
        if (t[0] == v) {                       // unique keys -> exactly one popper
#pragma unroll
            for (int i = 0; i < TOPK - 1; ++i) t[i] = t[i + 1];
            t[TOPK - 1] = 0xFFFFFFFFu;
        }
        if (lane == r) mine = v;
        if (r == 0) first = v;
        if (r == TOPK - 1) tenth = v;
    }
}

__device__ __forceinline__ float waveReduceSum(float v) {
#pragma unroll
    for (int off = 32; off >= 1; off >>= 1) v += __shfl_down(v, off, 64);
    return v;
}

// scan candidates in [s,e) of a y-sorted batch partition
__device__ __forceinline__ void scan_range(unsigned (&t)[TOPK], const uint2* __restrict__ base,
                                           int s, int e, int rz, int ry, int rx, int lane) {
    for (int i = s + lane; i < e; i += 64) {
        uint2 c = base[i];
        int dz = (int)((c.x >> 16) & 63u)  - rz;
        int dy = (int)((c.x >> 8)  & 255u) - ry;
        int dx = (int)(c.x & 255u)         - rx;
        unsigned d2 = (unsigned)(__mul24(dz, dz) + __mul24(dy, dy) + __mul24(dx, dx));
        unsigned key = (d2 << 14) | c.y;
        if (key < t[TOPK - 1]) insert_key(t, key);
    }
}

// ---------------------------------------------------------------- prep
// 4 blocks x 1024 threads; block b owns batch b. Counting-sort the batch's
// lidar by y (176 bins) into compacted, LDS histogram + prefix. Emits
// per-batch bin offsets (binoff_g[b*177+y]) so topk can scan a y-window.
// Order within a bin is nondeterministic == fine (keys carry idx tie-break).
__global__ __launch_bounds__(1024) void prep_kernel(
        const int* __restrict__ lidar_indices,
        unsigned* __restrict__ packed_full,
        uint2* __restrict__ compacted,
        int* __restrict__ binoff_g,
        int* __restrict__ ctrl) {   // [0..3]=batch count [4..7]=accum [8]=dctr
    __shared__ int hist[NBIN];
    __shared__ int binoff_s[NBIN + 1];
    __shared__ int bcur[NBIN];
    int tid = threadIdx.x, myb = blockIdx.x;
    if (tid < NBIN) hist[tid] = 0;

    // stage ALL loads up-front (static indices -> registers, latencies overlap)
    int4 li[NLID / 1024];
#pragma unroll
    for (int it = 0; it < NLID / 1024; ++it)
        li[it] = ((const int4*)lidar_indices)[it * 1024 + tid];
    __syncthreads();

    // histogram over y (= column 2, li.z)
#pragma unroll
    for (int it = 0; it < NLID / 1024; ++it)
        if (li[it].x == myb) atomicAdd(&hist[li[it].z], 1);
    __syncthreads();

    // exclusive prefix (small: 177 threads, <=176 LDS reads each)
    if (tid <= NBIN) {
        int s = 0;
        for (int j = 0; j < tid; ++j) s += hist[j];
        binoff_s[tid] = s;
    }
    __syncthreads();
    if (tid < NBIN) bcur[tid] = binoff_s[tid];
    __syncthreads();

    // scatter: y-sorted compacted + packed_full for the degenerate fallback
#pragma unroll
    for (int it = 0; it < NLID / 1024; ++it) {
        int i = it * 1024 + tid;
        unsigned pos = ((unsigned)li[it].y << 16) | ((unsigned)li[it].z << 8) | (unsigned)li[it].w;
        if (li[it].x == myb) {
            packed_full[i] = ((unsigned)li[it].x << 22) | pos;
            int dst = atomicAdd(&bcur[li[it].z], 1);
            compacted[myb * NLID + dst] = make_uint2(pos, (unsigned)i);
        }
    }

    __syncthreads();
    if (tid <= NBIN) binoff_g[myb * (NBIN + 1) + tid] = binoff_s[tid];
    if (tid == 0)    ctrl[myb] = binoff_s[NBIN];
    if (myb == 0 && tid >= 64 && tid < 69) ctrl[4 + (tid - 64)] = 0;  // accum[4]+dctr
}

// ---------------------------------------------------------------- top-10 NN (y-window pruned)
// One wave per radar row. Scan only candidates with |y-ry|<=16 (~770 of 4096);
// exact accept test: merged tenth d2 must beat the closest possible outside-
// window candidate. Rare reject (~1-3%, edge rows) rescans the two remaining
// strips (disjoint -> key uniqueness preserved). <10-in-batch rows fall back
// to the full packed scan (unchanged, exact).
__global__ __launch_bounds__(256) void topk_kernel(
        const uint2* __restrict__ compacted,
        const unsigned* __restrict__ packed_full,
        const int* __restrict__ ctrl,
        const int* __restrict__ binoff_g,
        const int* __restrict__ radar_indices,
        int* __restrict__ nn_out, int* __restrict__ matched_out) {
    int lane = threadIdx.x & 63;
    int row  = blockIdx.x * 4 + (threadIdx.x >> 6);
    int4 ri = ((const int4*)radar_indices)[row];
    int rb = ri.x, rz = ri.y, ry = ri.z, rx = ri.w;
    const int* boff = binoff_g + rb * (NBIN + 1);

    int lo = ry - 16; lo = lo < 0 ? 0 : lo;
    int hi = ry + 17; hi = hi > NBIN ? NBIN : hi;
    int s = boff[lo], e = boff[hi];

    unsigned t[TOPK];
#pragma unroll
    for (int i = 0; i < TOPK; ++i) t[i] = 0xFFFFFFFFu;

    const uint2* base = compacted + rb * NLID;
    scan_range(t, base, s, e, rz, ry, rx, lane);

    unsigned mine = 0xFFFFFFFFu, first = 0, tenth = 0;
    merge10(t, lane, mine, first, tenth);
    bool matched = true;

    // closest possible d2 outside the window (INF if window clipped that side)
    unsigned lim = 0xFFFFFFFFu;
    if (lo > 0)    { unsigned d = (unsigned)(ry - lo + 1); unsigned v = d * d; lim = v < lim ? v : lim; }
    if (hi < NBIN) { unsigned d = (unsigned)(hi - ry);     unsigned v = d * d; lim = v < lim ? v : lim; }

    if ((tenth >> 14) >= lim) {
        // expand to the full batch range, excluding already-scanned [s,e)
#pragma unroll
        for (int i = 0; i < TOPK; ++i) t[i] = 0xFFFFFFFFu;
        t[0] = mine;                                   // reseed (lanes>=10: FFFF no-op)
        scan_range(t, base, boff[0], s, rz, ry, rx, lane);
        scan_range(t, base, e, boff[NBIN], rz, ry, rx, lane);
        merge10(t, lane, mine, first, tenth);
    }

    if (tenth == 0xFFFFFFFFu) {
        // Degenerate row (<10 same-batch lidar): exact full scan w/ INF keys.
#pragma unroll
        for (int i = 0; i < TOPK; ++i) t[i] = 0xFFFFFFFFu;
        for (int it = 0; it < NLID / 256; ++it) {
            uint4 p4 = ((const uint4*)packed_full)[it * 64 + lane];
            unsigned bse = it * 256 + lane * 4;
            unsigned ps[4] = {p4.x, p4.y, p4.z, p4.w};
#pragma unroll
            for (int j = 0; j < 4; ++j) {
                unsigned p = ps[j];
                int b  = (int)(p >> 22);
                int dz = (int)((p >> 16) & 63u)  - rz;
                int dy = (int)((p >> 8)  & 255u) - ry;
                int dx = (int)(p & 255u)         - rx;
                unsigned d2 = (unsigned)(__mul24(dz, dz) + __mul24(dy, dy) + __mul24(dx, dx));
                unsigned hi2 = (b == rb) ? d2 : INF_D2;
                insert_key(t, (hi2 << 14) | (bse + j));
            }
        }
        merge10(t, lane, mine, first, tenth);
        matched = first < (INF_D2 << 14);
    }

    if (lane < TOPK) nn_out[row * TOPK + lane] = (int)(mine & 0x3FFFu);
    if (lane == 0)   matched_out[row] = matched ? 1 : 0;
}

// ---------------------------------------------------------------- MDN / occ / int (+fused finalize)
__global__ __launch_bounds__(256) void mdn_kernel(
        const float* __restrict__ mu_off, const float* __restrict__ log_sig_off,
        const float* __restrict__ mu_int, const float* __restrict__ occ_logit,
        const float* __restrict__ mix_logit, const float* __restrict__ lidar_features,
        const int* __restrict__ radar_indices, const int* __restrict__ lidar_indices,
        const int* __restrict__ nn, const int* __restrict__ matched,
        float* __restrict__ accum,            // {logp,int,occ,cnt}, zeroed by prep
        unsigned* __restrict__ dctr,          // zeroed by prep
        float* __restrict__ out) {
    int gid = blockIdx.x * 256 + threadIdx.x;
    int n  = gid / TOPK;
    int tt = gid - n * TOPK;
    int m  = matched[n];
    float mf = (float)m;
    int nni = nn[gid];

    int4 ri = ((const int4*)radar_indices)[n];
    int4 li = ((const int4*)lidar_indices)[nni];
    float y0 = mf * (float)(li.w - ri.w);
    float y1 = mf * (float)(li.z - ri.z);
    float y2 = mf * (float)(li.y - ri.y);

    float mix[KMIX];
    float mmax = -1e30f;
#pragma unroll
    for (int k = 0; k < KMIX; ++k) {
        mix[k] = mix_logit[n * KMIX + k];
        mmax = fmaxf(mmax, mix[k]);
    }
    float msum = 0.f;
#pragma unroll
    for (int k = 0; k < KMIX; ++k) msum += expf(mix[k] - mmax);
    float logZ = mmax + logf(msum);

    float lpost[KMIX];
    float pmax = -1e30f;
#pragma unroll
    for (int k = 0; k < KMIX; ++k) {
        int bidx = (n * KMIX + k) * 3;
        float mu0 = mu_off[bidx + 0], mu1 = mu_off[bidx + 1], mu2 = mu_off[bidx + 2];
        float l0 = log_sig_off[bidx + 0], l1 = log_sig_off[bidx + 1], l2 = log_sig_off[bidx + 2];
        float s0 = expf(2.f * l0) + 1e-12f;
        float s1 = expf(2.f * l1) + 1e-12f;
        float s2 = expf(2.f * l2) + 1e-12f;
        float d0 = y0 - mu0, d1 = y1 - mu1, d2v = y2 - mu2;
        float q = d0 * d0 / s0 + d1 * d1 / s1 + d2v * d2v / s2
                + 2.f * (l0 + l1 + l2) + 3.f * LOG2PI;
        lpost[k] = -0.5f * q + (mix[k] - logZ);
        pmax = fmaxf(pmax, lpost[k]);
    }
    float ex[KMIX];
    float se = 0.f;
#pragma unroll
    for (int k = 0; k < KMIX; ++k) { ex[k] = expf(lpost[k] - pmax); se += ex[k]; }
    float logp = pmax + logf(se);

    float gt = 0.f;
    if (m) {
        const float* lf = lidar_features + nni * CF;
        gt = 0.25f * (lf[3] + lf[7] + lf[11] + lf[15]);
    }
    float inv_se = 1.f / se;
    float isum = 0.f;
#pragma unroll
    for (int k = 0; k < KMIX; ++k)
        isum += ex[k] * inv_se * fabsf(mu_int[n * KMIX + k] - gt);

    float lp = mf * logp;
    float ip = mf * isum;
    float oc = 0.f, mc = 0.f;
    if (tt == 0) {
        float oa = -1e30f;
#pragma unroll
        for (int k = 0; k < KMIX; ++k) oa = fmaxf(oa, occ_logit[n * KMIX + k]);
        float soft_abs = log1pf(expf(-fabsf(oa)));
        oc = mf * (soft_abs + fmaxf(-oa, 0.f)) + (1.f - mf) * (soft_abs + fmaxf(oa, 0.f));
        mc = mf;
    }

    lp = waveReduceSum(lp); ip = waveReduceSum(ip);
    oc = waveReduceSum(oc); mc = waveReduceSum(mc);
    __shared__ float sA[4], sB[4], sC[4], sD[4];
    int wid = threadIdx.x >> 6, lane = threadIdx.x & 63;
    if (lane == 0) { sA[wid] = lp; sB[wid] = ip; sC[wid] = oc; sD[wid] = mc; }
    __syncthreads();
    if (threadIdx.x == 0) {
        atomicAdd(&accum[0], sA[0] + sA[1] + sA[2] + sA[3]);
        atomicAdd(&accum[1], sB[0] + sB[1] + sB[2] + sB[3]);
        atomicAdd(&accum[2], sC[0] + sC[1] + sC[2] + sC[3]);
        atomicAdd(&accum[3], sD[0] + sD[1] + sD[2] + sD[3]);
        __threadfence();
        unsigned done = atomicAdd(dctr, 1u);
        if (done == gridDim.x - 1) {          // last block finalizes
            __threadfence();
            float a = __hip_atomic_load(&accum[0], __ATOMIC_RELAXED, __HIP_MEMORY_SCOPE_AGENT);
            float b = __hip_atomic_load(&accum[1], __ATOMIC_RELAXED, __HIP_MEMORY_SCOPE_AGENT);
            float c = __hip_atomic_load(&accum[2], __ATOMIC_RELAXED, __HIP_MEMORY_SCOPE_AGENT);
            float d = __hip_atomic_load(&accum[3], __ATOMIC_RELAXED, __HIP_MEMORY_SCOPE_AGENT);
            float occ_loss = c / (float)NRAD;
            float mdn_nll  = -a / (d * (float)TOPK);
            float int_loss = b / (d * (float)TOPK * (float)KMIX);
            out[0] = 0.2f * occ_loss + mdn_nll + 0.1f * int_loss;
        }
    }
}

// ---------------------------------------------------------------- launch
extern "C" void kernel_launch(void* const* d_in, const int* in_sizes, int n_in,
                              void* d_out, int out_size, void* d_ws, size_t ws_size,
                              hipStream_t stream) {
    const float* mu_off         = (const float*)d_in[0];
    const float* log_sig_off    = (const float*)d_in[1];
    const float* mu_int         = (const float*)d_in[2];
    const float* occ_logit      = (const float*)d_in[3];
    const float* mix_logit      = (const float*)d_in[4];
    const float* lidar_features = (const float*)d_in[5];
    const int*   radar_indices  = (const int*)d_in[6];
    const int*   lidar_indices  = (const int*)d_in[7];
    float* out = (float*)d_out;

    char* ws = (char*)d_ws;
    unsigned* packed_full = (unsigned*)(ws + 0);         //  64 KB
    uint2*    compacted   = (uint2*)(ws + 65536);        //  512 KB (y-sorted per batch)
    int*      ctrl        = (int*)(ws + 589824);         //  64 B (cnt/accum/dctr)
    int*      nn          = (int*)(ws + 589888);         //  160 KB
    int*      matched     = (int*)(ws + 753728);         //  16 KB
    int*      binoff_g    = (int*)(ws + 770112);         //  4*177*4 = 2832 B

    float*    accum = (float*)(ctrl + 4);
    unsigned* dctr  = (unsigned*)(ctrl + 8);

    hipLaunchKernelGGL(prep_kernel, dim3(4), dim3(1024), 0, stream,
                       lidar_indices, packed_full, compacted, binoff_g, ctrl);
    hipLaunchKernelGGL(topk_kernel, dim3(NRAD / 4), dim3(256), 0, stream,
                       compacted, packed_full, ctrl, binoff_g, radar_indices, nn, matched);
    hipLaunchKernelGGL(mdn_kernel, dim3(NRAD * TOPK / 256), dim3(256), 0, stream,
                       mu_off, log_sig_off, mu_int, occ_logit, mix_logit,
                       lidar_features, radar_indices, lidar_indices,
                       nn, matched, accum, dctr, out);
}